// Round 10
// baseline (5397.890 us; speedup 1.0000x reference)
//
#include <hip/hip_runtime.h>

// SpikeMLP — bit-exact fp32-chain replication, round 10.
// Established (R1-R9): ref = fp32 summation chain on RAW f32 inputs
// (quantized-input and all-f64 hypotheses refuted; pipeline validated by two
// agreeing independent exact builds). Tried chains (all single-acc ascending
// FMA panels): 384/384/256, 384/320/320, 320/320/192/192 — all wrong.
// This round: K panels 512/512 — covers the P/Q-swapped OpenBLAS configs
// (kc = 768 or 640 > K/2 -> driver even-split rule gives 512/512) and any
// Q >= 512 build. Per C element: single accumulator, k-ascending FMA per
// panel; C = (p0 + p1). Recurrence: fp32, numpy ufunc order, contraction off.

typedef __bf16 bf16x8_t __attribute__((ext_vector_type(8)));

static constexpr int BSZ   = 4096;
static constexpr int D_IN  = 1024;
static constexpr int H1    = 1024;
static constexpr int D_OUT = 512;
static constexpr int M_ROWS = BSZ * 16;   // 65536, m = b*16 + t

// ---------------------------------------------------------------------------
// pack X [B, D_in, T=16] f32 -> A [m = b*16 + t][d] bf16 (spikes exactly 0/1)
// ---------------------------------------------------------------------------
__global__ void pack_x(const float* __restrict__ X, __bf16* __restrict__ A) {
    const int P = blockIdx.x * 256 + threadIdx.x;     // P = b*1024 + d
    const int b = P >> 10, d = P & 1023;
    const float4* xp = (const float4*)(X + (size_t)P * 16);
    float4 x0 = xp[0], x1 = xp[1], x2 = xp[2], x3 = xp[3];
    const float v[16] = {x0.x, x0.y, x0.z, x0.w, x1.x, x1.y, x1.z, x1.w,
                         x2.x, x2.y, x2.z, x2.w, x3.x, x3.y, x3.z, x3.w};
#pragma unroll
    for (int t = 0; t < 16; ++t)
        A[((size_t)(b * 16 + t)) * 1024 + d] = (__bf16)v[t];
}

// ---------------------------------------------------------------------------
// GEMM with candidate fp32 accumulation order.
// C[m][n] = A[m,:] . W[n,:], K = 1024. Block: 64x64 tile, 256 thr, 4x4 each.
// Panel boundary: k = 512 -> flush after kt = 15 and kt = 31.
// ---------------------------------------------------------------------------
__global__ __launch_bounds__(256) void gemm_np(
    const __bf16* __restrict__ A,   // [M, 1024] spikes (values exactly 0/1)
    const float* __restrict__ W,    // [N, 1024] fp32 weights (raw input)
    float* __restrict__ C,          // [M, N] fp32
    int N) {
#pragma clang fp contract(off)
    __shared__ float As[64][36];    // +4 pad
    __shared__ float Ws[64][36];

    const int tid = threadIdx.x;
    const int tx = tid & 15, ty = tid >> 4;
    const int m0 = blockIdx.x * 64, n0 = blockIdx.y * 64;
    const int srow = tid >> 2, scol = (tid & 3) * 8;

    float pacc[4][4] = {};   // current-panel accumulators
    float tot[4][4]  = {};   // sum of completed panels

    for (int kt = 0; kt < 32; ++kt) {
        const int k0 = kt * 32;
        bf16x8_t av = *(const bf16x8_t*)(A + (size_t)(m0 + srow) * 1024 + k0 + scol);
        float4 w0 = *(const float4*)(W + (size_t)(n0 + srow) * 1024 + k0 + scol);
        float4 w1 = *(const float4*)(W + (size_t)(n0 + srow) * 1024 + k0 + scol + 4);
#pragma unroll
        for (int e = 0; e < 8; ++e)
            As[srow][scol + e] = (float)av[e];
        *(float4*)&Ws[srow][scol]     = w0;
        *(float4*)&Ws[srow][scol + 4] = w1;
        __syncthreads();

        for (int kk = 0; kk < 32; ++kk) {
            float a[4], w[4];
#pragma unroll
            for (int i = 0; i < 4; ++i) a[i] = As[ty + i * 16][kk];
#pragma unroll
            for (int j = 0; j < 4; ++j) w[j] = Ws[tx + j * 16][kk];
#pragma unroll
            for (int i = 0; i < 4; ++i)
#pragma unroll
                for (int j = 0; j < 4; ++j)
                    pacc[i][j] = __builtin_fmaf(a[i], w[j], pacc[i][j]);
        }
        __syncthreads();

        // K-chain candidate: two even panels of 512 -> flush at k = 512, 1024
        if (kt == 15 || kt == 31) {
#pragma unroll
            for (int i = 0; i < 4; ++i)
#pragma unroll
                for (int j = 0; j < 4; ++j) {
                    tot[i][j] = tot[i][j] + pacc[i][j];
                    pacc[i][j] = 0.0f;
                }
        }
    }

#pragma unroll
    for (int i = 0; i < 4; ++i)
#pragma unroll
        for (int j = 0; j < 4; ++j)
            C[(size_t)(m0 + ty + i * 16) * N + (n0 + tx + j * 16)] = tot[i][j];
}

// ---------------------------------------------------------------------------
// fp32 LIF recurrence, numpy ufunc order, contraction off.
// cur = (cur*0.5 + z) + b; volt = ((volt*0.75)*(1-s)) + cur; s = volt > 0.5
// ---------------------------------------------------------------------------
__global__ void recur_hidden(const float* __restrict__ Z, const float* __restrict__ bias,
                             __bf16* __restrict__ S) {
#pragma clang fp contract(off)
    const int idx = blockIdx.x * 256 + threadIdx.x;   // b*1024 + n
    const int n = idx & 1023, b = idx >> 10;
    const float bb = bias[n];
    float c = 0.f, v = 0.f, s = 0.f;
#pragma unroll
    for (int t = 0; t < 16; ++t) {
        const float z = Z[(size_t)(b * 16 + t) * 1024 + n];
        const float t1 = c * 0.5f;
        const float t2 = t1 + z;
        c = t2 + bb;
        const float u1 = v * 0.75f;
        const float u2 = u1 * (1.0f - s);
        v = u2 + c;
        s = (v > 0.5f) ? 1.0f : 0.0f;
        S[(size_t)(b * 16 + t) * 1024 + n] = (__bf16)s;   // exact 0/1
    }
}

__global__ void recur_out(const float* __restrict__ Z, const float* __restrict__ bias,
                          float* __restrict__ Out) {
#pragma clang fp contract(off)
    const int idx = blockIdx.x * 256 + threadIdx.x;   // b*512 + n
    const int n = idx & 511, b = idx >> 9;
    const float bb = bias[n];
    float c = 0.f, v = 0.f, s = 0.f, acm = 0.f;
#pragma unroll
    for (int t = 0; t < 16; ++t) {
        const float z = Z[(size_t)(b * 16 + t) * 512 + n];
        const float t1 = c * 0.5f;
        const float t2 = t1 + z;
        c = t2 + bb;
        const float u1 = v * 0.75f;
        const float u2 = u1 * (1.0f - s);
        v = u2 + c;
        s = (v > 0.5f) ? 1.0f : 0.0f;
        acm += s;                                     // small ints, exact
    }
    Out[(size_t)b * 512 + n] = acm * 0.0625f;         // exact (2^-4)
}

// ---------------------------------------------------------------------------
extern "C" void kernel_launch(void* const* d_in, const int* in_sizes, int n_in,
                              void* d_out, int out_size, void* d_ws, size_t ws_size,
                              hipStream_t stream) {
    const float* X  = (const float*)d_in[0];
    const float* W1 = (const float*)d_in[1];
    const float* b1 = (const float*)d_in[2];
    const float* W2 = (const float*)d_in[3];
    const float* b2 = (const float*)d_in[4];
    const float* Wo = (const float*)d_in[5];
    const float* bo = (const float*)d_in[6];

    char* ws = (char*)d_ws;
    __bf16* A1 = (__bf16*)ws;                      // 128 MiB (reused as S2)
    __bf16* S1 = (__bf16*)(ws + (128ull << 20));   // 128 MiB
    float*  Z  = (float*)(ws + (256ull << 20));    // 256 MiB ([M, 1024] f32)
    __bf16* S2 = A1;

    pack_x<<<(BSZ * D_IN) / 256, 256, 0, stream>>>(X, A1);

    // layer 1
    gemm_np<<<dim3(M_ROWS / 64, H1 / 64), 256, 0, stream>>>(A1, W1, Z, H1);
    recur_hidden<<<(BSZ * H1) / 256, 256, 0, stream>>>(Z, b1, S1);
    // layer 2
    gemm_np<<<dim3(M_ROWS / 64, H1 / 64), 256, 0, stream>>>(S1, W2, Z, H1);
    recur_hidden<<<(BSZ * H1) / 256, 256, 0, stream>>>(Z, b2, S2);
    // output layer
    gemm_np<<<dim3(M_ROWS / 64, D_OUT / 64), 256, 0, stream>>>(S2, Wo, Z, D_OUT);
    recur_out<<<(BSZ * D_OUT) / 256, 256, 0, stream>>>(Z, bo, (float*)d_out);
}

// Round 11
// 4087.644 us; speedup vs baseline: 1.3205x; 1.3205x over previous
//
#include <hip/hip_runtime.h>

// SpikeMLP — R11: validated bit-exact chain (panels 512/512, single-acc
// ascending FMA; fp32 ufunc recurrence) + GEMM restructured for VALU peak.
// Correctness contract (FROZEN, R10 passed absmax=0):
//   per C element: pacc = fma(a_k, w_k, pacc) for k ascending; flush
//   tot = tot + pacc after k=512 and k=1024. Recurrence fp32, ufunc order,
//   contraction off. Any layout change must preserve this exact sequence.
// Perf changes vs R10 (identical arithmetic, different mapping):
//   - k-major f32 LDS tiles -> operand reads are ds_read_b128
//   - 8x4 elems/thread (tile 128x64): 32 FMA per 3 LDS reads per kk
//   - staged bf16->f32 convert once; coalesced float4 C stores

typedef __bf16 bf16x8_t __attribute__((ext_vector_type(8)));

static constexpr int BSZ   = 4096;
static constexpr int D_IN  = 1024;
static constexpr int H1    = 1024;
static constexpr int D_OUT = 512;
static constexpr int M_ROWS = BSZ * 16;   // 65536, m = b*16 + t

// ---------------------------------------------------------------------------
// pack X [B, D_in, T=16] f32 -> A [m = b*16 + t][d] bf16 (spikes exactly 0/1)
// ---------------------------------------------------------------------------
__global__ void pack_x(const float* __restrict__ X, __bf16* __restrict__ A) {
    const int P = blockIdx.x * 256 + threadIdx.x;     // P = b*1024 + d
    const int b = P >> 10, d = P & 1023;
    const float4* xp = (const float4*)(X + (size_t)P * 16);
    float4 x0 = xp[0], x1 = xp[1], x2 = xp[2], x3 = xp[3];
    const float v[16] = {x0.x, x0.y, x0.z, x0.w, x1.x, x1.y, x1.z, x1.w,
                         x2.x, x2.y, x2.z, x2.w, x3.x, x3.y, x3.z, x3.w};
#pragma unroll
    for (int t = 0; t < 16; ++t)
        A[((size_t)(b * 16 + t)) * 1024 + d] = (__bf16)v[t];
}

// ---------------------------------------------------------------------------
// GEMM, reference fp32 chain. C[m][n] = A[m,:] . W[n,:], K = 1024.
// Block 128(M) x 64(N), 256 threads, 8x4 per thread. BK = 32, k-major LDS.
// Panel flush after kt = 15 (k=512) and kt = 31 (k=1024) — DO NOT CHANGE.
// ---------------------------------------------------------------------------
__global__ __launch_bounds__(256) void gemm_np(
    const __bf16* __restrict__ A,   // [M, 1024] spikes (values exactly 0/1)
    const float* __restrict__ W,    // [N, 1024] fp32 weights (raw input)
    float* __restrict__ C,          // [M, N] fp32
    int N) {
#pragma clang fp contract(off)
    __shared__ float As[32][128];   // [kk][m]  16 KB
    __shared__ float Ws[32][64];    // [kk][n]   8 KB

    const int tid = threadIdx.x;
    const int tx = tid & 15;        // n group: cols tx*4 .. tx*4+3
    const int ty = tid >> 4;        // m group: rows ty*8 .. ty*8+7
    const int m0 = blockIdx.x * 128, n0 = blockIdx.y * 64;

    const int arow = tid & 127, akh = tid >> 7;   // A staging: row, k-half
    const int wrow = tid & 63,  wks = tid >> 6;   // W staging: row, k-quarter

    const __bf16* Ab = A + (size_t)(m0 + arow) * 1024 + akh * 16;
    const float*  Wb = W + (size_t)(n0 + wrow) * 1024 + wks * 8;

    float pacc[8][4] = {};   // current-panel accumulators
    float tot[8][4]  = {};   // sum of completed panels

    for (int kt = 0; kt < 32; ++kt) {
        const int k0 = kt * 32;
        // global reads (issue before barrier)
        bf16x8_t av0 = *(const bf16x8_t*)(Ab + k0);
        bf16x8_t av1 = *(const bf16x8_t*)(Ab + k0 + 8);
        float4   wv0 = *(const float4*)(Wb + k0);
        float4   wv1 = *(const float4*)(Wb + k0 + 4);
        __syncthreads();             // previous tile fully consumed
#pragma unroll
        for (int e = 0; e < 8; ++e) {
            As[akh * 16 + e][arow]     = (float)av0[e];
            As[akh * 16 + 8 + e][arow] = (float)av1[e];
        }
        Ws[wks * 8 + 0][wrow] = wv0.x;
        Ws[wks * 8 + 1][wrow] = wv0.y;
        Ws[wks * 8 + 2][wrow] = wv0.z;
        Ws[wks * 8 + 3][wrow] = wv0.w;
        Ws[wks * 8 + 4][wrow] = wv1.x;
        Ws[wks * 8 + 5][wrow] = wv1.y;
        Ws[wks * 8 + 6][wrow] = wv1.z;
        Ws[wks * 8 + 7][wrow] = wv1.w;
        __syncthreads();

#pragma unroll
        for (int kk = 0; kk < 32; ++kk) {         // strictly k-ascending
            float4 a0 = *(const float4*)&As[kk][ty * 8];
            float4 a1 = *(const float4*)&As[kk][ty * 8 + 4];
            float4 w  = *(const float4*)&Ws[kk][tx * 4];
            const float a[8] = {a0.x, a0.y, a0.z, a0.w, a1.x, a1.y, a1.z, a1.w};
            const float ww[4] = {w.x, w.y, w.z, w.w};
#pragma unroll
            for (int i = 0; i < 8; ++i)
#pragma unroll
                for (int j = 0; j < 4; ++j)
                    pacc[i][j] = __builtin_fmaf(a[i], ww[j], pacc[i][j]);
        }

        // reference K-chain: flush at k = 512 and k = 1024 (frozen)
        if (kt == 15 || kt == 31) {
#pragma unroll
            for (int i = 0; i < 8; ++i)
#pragma unroll
                for (int j = 0; j < 4; ++j) {
                    tot[i][j] = tot[i][j] + pacc[i][j];
                    pacc[i][j] = 0.0f;
                }
        }
    }

#pragma unroll
    for (int i = 0; i < 8; ++i) {
        float4 st = {tot[i][0], tot[i][1], tot[i][2], tot[i][3]};
        *(float4*)&C[(size_t)(m0 + ty * 8 + i) * N + (n0 + tx * 4)] = st;
    }
}

// ---------------------------------------------------------------------------
// fp32 LIF recurrence, numpy ufunc order, contraction off (frozen).
// ---------------------------------------------------------------------------
__global__ void recur_hidden(const float* __restrict__ Z, const float* __restrict__ bias,
                             __bf16* __restrict__ S) {
#pragma clang fp contract(off)
    const int idx = blockIdx.x * 256 + threadIdx.x;   // b*1024 + n
    const int n = idx & 1023, b = idx >> 10;
    const float bb = bias[n];
    float c = 0.f, v = 0.f, s = 0.f;
#pragma unroll
    for (int t = 0; t < 16; ++t) {
        const float z = Z[(size_t)(b * 16 + t) * 1024 + n];
        const float t1 = c * 0.5f;
        const float t2 = t1 + z;
        c = t2 + bb;
        const float u1 = v * 0.75f;
        const float u2 = u1 * (1.0f - s);
        v = u2 + c;
        s = (v > 0.5f) ? 1.0f : 0.0f;
        S[(size_t)(b * 16 + t) * 1024 + n] = (__bf16)s;   // exact 0/1
    }
}

__global__ void recur_out(const float* __restrict__ Z, const float* __restrict__ bias,
                          float* __restrict__ Out) {
#pragma clang fp contract(off)
    const int idx = blockIdx.x * 256 + threadIdx.x;   // b*512 + n
    const int n = idx & 511, b = idx >> 9;
    const float bb = bias[n];
    float c = 0.f, v = 0.f, s = 0.f, acm = 0.f;
#pragma unroll
    for (int t = 0; t < 16; ++t) {
        const float z = Z[(size_t)(b * 16 + t) * 512 + n];
        const float t1 = c * 0.5f;
        const float t2 = t1 + z;
        c = t2 + bb;
        const float u1 = v * 0.75f;
        const float u2 = u1 * (1.0f - s);
        v = u2 + c;
        s = (v > 0.5f) ? 1.0f : 0.0f;
        acm += s;                                     // small ints, exact
    }
    Out[(size_t)b * 512 + n] = acm * 0.0625f;         // exact (2^-4)
}

// ---------------------------------------------------------------------------
extern "C" void kernel_launch(void* const* d_in, const int* in_sizes, int n_in,
                              void* d_out, int out_size, void* d_ws, size_t ws_size,
                              hipStream_t stream) {
    const float* X  = (const float*)d_in[0];
    const float* W1 = (const float*)d_in[1];
    const float* b1 = (const float*)d_in[2];
    const float* W2 = (const float*)d_in[3];
    const float* b2 = (const float*)d_in[4];
    const float* Wo = (const float*)d_in[5];
    const float* bo = (const float*)d_in[6];

    char* ws = (char*)d_ws;
    __bf16* A1 = (__bf16*)ws;                      // 128 MiB (reused as S2)
    __bf16* S1 = (__bf16*)(ws + (128ull << 20));   // 128 MiB
    float*  Z  = (float*)(ws + (256ull << 20));    // 256 MiB ([M, 1024] f32)
    __bf16* S2 = A1;

    pack_x<<<(BSZ * D_IN) / 256, 256, 0, stream>>>(X, A1);

    // layer 1
    gemm_np<<<dim3(M_ROWS / 128, H1 / 64), 256, 0, stream>>>(A1, W1, Z, H1);
    recur_hidden<<<(BSZ * H1) / 256, 256, 0, stream>>>(Z, b1, S1);
    // layer 2
    gemm_np<<<dim3(M_ROWS / 128, H1 / 64), 256, 0, stream>>>(S1, W2, Z, H1);
    recur_hidden<<<(BSZ * H1) / 256, 256, 0, stream>>>(Z, b2, S2);
    // output layer
    gemm_np<<<dim3(M_ROWS / 128, D_OUT / 64), 256, 0, stream>>>(S2, Wo, Z, D_OUT);
    recur_out<<<(BSZ * D_OUT) / 256, 256, 0, stream>>>(Z, bo, (float*)d_out);
}